// Round 1
// baseline (572.874 us; speedup 1.0000x reference)
//
#include <hip/hip_runtime.h>
#include <hip/hip_bf16.h>

// ClassAtt fused pipeline, bf16-MFMA implementation (m97-style 128x128 GEMM tiles).
// Stages: cvt(f32->bf16) -> G1 expert block-diag -> G2 hidden -> attn/softmax/context
//         -> G4 decode1 -> G5 decode2 (fp32 out).

typedef __bf16 bf16_t;
typedef __bf16 bf16x4 __attribute__((ext_vector_type(4)));
typedef __bf16 bf16x8 __attribute__((ext_vector_type(8)));
typedef float  f32x4  __attribute__((ext_vector_type(4)));

#define AS1(p) (const __attribute__((address_space(1))) void*)(p)
#define AS3(p) (__attribute__((address_space(3))) void*)(p)

// ---------------- f32 -> bf16 conversion (vectorized, zero-pad tail) ----------------
__global__ void cvt_f32_bf16_v4(const float* __restrict__ src, bf16_t* __restrict__ dst,
                                int n4src, int n4tot) {
  for (int i = blockIdx.x * blockDim.x + threadIdx.x; i < n4tot; i += gridDim.x * blockDim.x) {
    bf16x4 o;
    if (i < n4src) {
      float4 f = ((const float4*)src)[i];
      o[0] = (bf16_t)f.x; o[1] = (bf16_t)f.y; o[2] = (bf16_t)f.z; o[3] = (bf16_t)f.w;
    } else {
      o[0] = (bf16_t)0.0f; o[1] = (bf16_t)0.0f; o[2] = (bf16_t)0.0f; o[3] = (bf16_t)0.0f;
    }
    *(bf16x4*)(dst + (size_t)i * 4) = o;
  }
}

__global__ void concat_bias3(const float* __restrict__ a, const float* __restrict__ b,
                             const float* __restrict__ c, float* __restrict__ dst) {
  int i = blockIdx.x * blockDim.x + threadIdx.x;
  if (i < 1024) dst[i] = a[i];
  else if (i < 2048) dst[i] = b[i - 1024];
  else if (i < 3072) dst[i] = c[i - 2048];
}

// ---------------- GEMM: C = act(A @ Bw^T + bias) ----------------
// A: M x lda (bf16), Bw: N x ldb row-major weights (bf16) -> B^T layout for MFMA.
// 128x128 tile, BK=32, 4 waves each computing 64x64 via 4x4 of 16x16x32 MFMA.
// BDIAG: expert layer -- A column offset = (colBase/1024)*512, K=512.
template<bool BDIAG, bool RELU, bool OUT_BF16>
__global__ __launch_bounds__(256, 2)
void gemm_bt(const bf16_t* __restrict__ A, int lda,
             const bf16_t* __restrict__ Bw, int ldb,
             const float* __restrict__ bias,
             void* __restrict__ Cout, int ldc,
             int K, int Nmask)
{
  __shared__ __attribute__((aligned(16))) bf16_t As[128 * 32];
  __shared__ __attribute__((aligned(16))) bf16_t Bs[128 * 32];

  const int t   = threadIdx.x;
  const int l   = t & 63;
  const int w   = t >> 6;
  const int l15 = l & 15, lhi = l >> 4;
  const int wr  = w >> 1, wc = w & 1;      // wave -> 64x64 quadrant
  const int rowBase = blockIdx.y * 128;
  const int colBase = blockIdx.x * 128;

  int aCol0 = 0;
  if (BDIAG) aCol0 = (colBase >> 10) * 512;

  // staging: thread t loads 16B group g=t and g=t+256; row=g>>2, k-off=(g&3)*8
  const int r0  = t >> 2;
  const int kk0 = (t & 3) * 8;

  f32x4 acc[4][4] = {};

  const bf16_t* aBase = A  + (size_t)rowBase * lda + aCol0 + kk0;
  const bf16_t* bBase = Bw + (size_t)colBase * ldb + kk0;

  for (int k0 = 0; k0 < K; k0 += 32) {
    #pragma unroll
    for (int i = 0; i < 2; i++) {
      const int r  = r0 + i * 64;
      const int g8 = (t + i * 256) * 8;   // LDS element offset (16B groups, lane-linear per wave)
      __builtin_amdgcn_global_load_lds(AS1(aBase + (size_t)r * lda + k0), AS3(&As[g8]), 16, 0, 0);
      __builtin_amdgcn_global_load_lds(AS1(bBase + (size_t)r * ldb + k0), AS3(&Bs[g8]), 16, 0, 0);
    }
    __syncthreads();   // drains vmcnt(0) before barrier (compiler-emitted)

    bf16x8 af[4], bfr[4];
    #pragma unroll
    for (int m = 0; m < 4; m++)
      af[m] = *(const bf16x8*)(&As[(wr * 64 + m * 16 + l15) * 32 + lhi * 8]);
    #pragma unroll
    for (int n = 0; n < 4; n++)
      bfr[n] = *(const bf16x8*)(&Bs[(wc * 64 + n * 16 + l15) * 32 + lhi * 8]);

    #pragma unroll
    for (int m = 0; m < 4; m++)
      #pragma unroll
      for (int n = 0; n < 4; n++)
        acc[m][n] = __builtin_amdgcn_mfma_f32_16x16x32_bf16(af[m], bfr[n], acc[m][n], 0, 0, 0);

    __syncthreads();   // all reads done before next-iter staging overwrites LDS
  }

  // epilogue: D row = 4*(l>>4)+i, col = l&15 (verified gfx950 C/D layout)
  #pragma unroll
  for (int m = 0; m < 4; m++) {
    const int row = rowBase + wr * 64 + m * 16 + lhi * 4;
    #pragma unroll
    for (int n = 0; n < 4; n++) {
      const int col = colBase + wc * 64 + n * 16 + l15;
      const float bv = (col < Nmask) ? bias[col] : 0.0f;
      #pragma unroll
      for (int i = 0; i < 4; i++) {
        float v = acc[m][n][i] + bv;
        if (RELU) v = fmaxf(v, 0.0f);
        if (OUT_BF16) {
          ((bf16_t*)Cout)[(size_t)(row + i) * ldc + col] = (bf16_t)v;
        } else {
          if (col < Nmask) ((float*)Cout)[(size_t)(row + i) * ldc + col] = v;
        }
      }
    }
  }
}

// ---------------- alphas -> softmax -> context (one block per row) ----------------
// P: B x 3072 (P1|P2|P3), ds: B x 2048 with cols [1024:2048] = last_hid (already written).
// Writes ds cols [0:1024] = context.
__global__ __launch_bounds__(256)
void attn_ctx(const bf16_t* __restrict__ P, bf16_t* __restrict__ ds) {
  __shared__ float red[3][4];
  __shared__ float wsh[3];
  const int r = blockIdx.x;
  const int t = threadIdx.x;
  const bf16_t* Prow = P + (size_t)r * 3072;
  bf16_t* dsrow = ds + (size_t)r * 2048;

  const int j = t * 4;
  bf16x4 lv = *(const bf16x4*)(dsrow + 1024 + j);
  float lhv[4], pv[3][4];
  float s[3] = {0.f, 0.f, 0.f};
  #pragma unroll
  for (int q = 0; q < 4; q++) lhv[q] = (float)lv[q];
  #pragma unroll
  for (int e = 0; e < 3; e++) {
    bf16x4 p = *(const bf16x4*)(Prow + e * 1024 + j);
    #pragma unroll
    for (int q = 0; q < 4; q++) {
      pv[e][q] = (float)p[q];
      s[e] += lhv[q] * pv[e][q];
    }
  }
  #pragma unroll
  for (int off = 32; off > 0; off >>= 1) {
    #pragma unroll
    for (int e = 0; e < 3; e++) s[e] += __shfl_down(s[e], off, 64);
  }
  const int w = t >> 6, l = t & 63;
  if (l == 0) {
    #pragma unroll
    for (int e = 0; e < 3; e++) red[e][w] = s[e];
  }
  __syncthreads();
  if (t == 0) {
    float a0 = red[0][0] + red[0][1] + red[0][2] + red[0][3];
    float a1 = red[1][0] + red[1][1] + red[1][2] + red[1][3];
    float a2 = red[2][0] + red[2][1] + red[2][2] + red[2][3];
    float mx = fmaxf(a0, fmaxf(a1, a2));
    float e0 = expf(a0 - mx), e1 = expf(a1 - mx), e2 = expf(a2 - mx);
    float inv = 1.0f / (e0 + e1 + e2);
    wsh[0] = e0 * inv; wsh[1] = e1 * inv; wsh[2] = e2 * inv;
  }
  __syncthreads();
  const float w0 = wsh[0], w1 = wsh[1], w2 = wsh[2];
  bf16x4 o;
  #pragma unroll
  for (int q = 0; q < 4; q++)
    o[q] = (bf16_t)(w0 * pv[0][q] + w1 * pv[1][q] + w2 * pv[2][q]);
  *(bf16x4*)(dsrow + j) = o;
}

// ---------------- launch ----------------
extern "C" void kernel_launch(void* const* d_in, const int* in_sizes, int n_in,
                              void* d_out, int out_size, void* d_ws, size_t ws_size,
                              hipStream_t stream) {
  (void)in_sizes; (void)n_in; (void)out_size; (void)ws_size;

  const float* tube = (const float*)d_in[0];
  const float* w1W  = (const float*)d_in[1];
  const float* w1b  = (const float*)d_in[2];
  const float* w2W  = (const float*)d_in[3];
  const float* w2b  = (const float*)d_in[4];
  const float* w3W  = (const float*)d_in[5];
  const float* w3b  = (const float*)d_in[6];
  const float* whW  = (const float*)d_in[7];
  const float* whb  = (const float*)d_in[8];
  const float* wd1W = (const float*)d_in[9];
  const float* wd1b = (const float*)d_in[10];
  const float* wd2W = (const float*)d_in[11];
  const float* wd2b = (const float*)d_in[12];

  // workspace layout (bytes); out1 aliases {whB, w123B, tubeB} which are dead by G4.
  char* ws = (char*)d_ws;
  bf16_t* P       = (bf16_t*)(ws + 0);            // 16384x3072  (100,663,296 B)
  bf16_t* ds      = (bf16_t*)(ws + 100663296);    // 16384x2048  ( 67,108,864 B)
  bf16_t* wd1B    = (bf16_t*)(ws + 167772160);    // 2048x2048   (  8,388,608 B)
  bf16_t* wd2B    = (bf16_t*)(ws + 176160768);    // 1024x2048 padded (4,194,304 B)
  bf16_t* whB     = (bf16_t*)(ws + 180355072);    // 1024x3072   (  6,291,456 B)
  bf16_t* w123B   = (bf16_t*)(ws + 186646528);    // 3072x512    (  3,145,728 B)
  bf16_t* tubeB   = (bf16_t*)(ws + 189792256);    // 16384x1536  ( 50,331,648 B)
  bf16_t* out1    = (bf16_t*)(ws + 180355072);    // 16384x2048, aliases whB..tubeB
  float*  bias123 = (float*)(ws + 247463936);     // 3072 f32
  // total: 247,476,224 B

  auto cvt = [&](const float* s, bf16_t* d, int n4s, int n4t) {
    int nb = (n4t + 255) / 256; if (nb > 2048) nb = 2048;
    hipLaunchKernelGGL(cvt_f32_bf16_v4, dim3(nb), dim3(256), 0, stream, s, d, n4s, n4t);
  };
  cvt(tube, tubeB, 6291456, 6291456);        // 16384*1536/4
  cvt(w1W,  w123B,           131072, 131072);
  cvt(w2W,  w123B +  524288, 131072, 131072);
  cvt(w3W,  w123B + 1048576, 131072, 131072);
  cvt(whW,  whB,  786432, 786432);
  cvt(wd1W, wd1B, 1048576, 1048576);
  cvt(wd2W, wd2B, 512000, 524288);           // zero-pad rows 1000..1023
  hipLaunchKernelGGL(concat_bias3, dim3(12), dim3(256), 0, stream, w1b, w2b, w3b, bias123);

  // G1: P = relu(block-diag expert GEMM), N=3072, K=512 per block
  hipLaunchKernelGGL((gemm_bt<true, true, true>), dim3(24, 128), dim3(256), 0, stream,
                     tubeB, 1536, w123B, 512, bias123, (void*)P, 3072, 512, 3072);
  // G2: ds[:,1024:2048] = relu(P @ wh^T + b), N=1024, K=3072
  hipLaunchKernelGGL((gemm_bt<false, true, true>), dim3(8, 128), dim3(256), 0, stream,
                     P, 3072, whB, 3072, whb, (void*)(ds + 1024), 2048, 3072, 1024);
  // attn: alphas -> softmax -> context into ds[:,0:1024]
  hipLaunchKernelGGL(attn_ctx, dim3(16384), dim3(256), 0, stream, P, ds);
  // G4: out1 = relu(ds @ wd1^T + b), N=2048, K=2048
  hipLaunchKernelGGL((gemm_bt<false, true, true>), dim3(16, 128), dim3(256), 0, stream,
                     ds, 2048, wd1B, 2048, wd1b, (void*)out1, 2048, 2048, 2048);
  // G5: out = out1 @ wd2^T + b (fp32, N masked to 1000), K=2048
  hipLaunchKernelGGL((gemm_bt<false, false, false>), dim3(8, 128), dim3(256), 0, stream,
                     out1, 2048, wd2B, 2048, wd2b, d_out, 1000, 2048, 1000);
}

// Round 2
// 426.297 us; speedup vs baseline: 1.3438x; 1.3438x over previous
//
#include <hip/hip_runtime.h>
#include <hip/hip_bf16.h>

// ClassAtt fused pipeline. GEMMs: 256x256-tile, BK=32, 4-deep-ring pipelined
// bf16 MFMA (counted vmcnt, LDS XOR-swizzle, setprio, XCD swizzle).

typedef __bf16 bf16_t;
typedef __bf16 bf16x4 __attribute__((ext_vector_type(4)));
typedef __bf16 bf16x8 __attribute__((ext_vector_type(8)));
typedef float  f32x4  __attribute__((ext_vector_type(4)));

#define AS1(p) (const __attribute__((address_space(1))) void*)(p)
#define AS3(p) (__attribute__((address_space(3))) void*)(p)

// ---------------- f32 -> bf16 conversion (vectorized, zero-pad tail) ----------------
__global__ void cvt_f32_bf16_v4(const float* __restrict__ src, bf16_t* __restrict__ dst,
                                int n4src, int n4tot) {
  for (int i = blockIdx.x * blockDim.x + threadIdx.x; i < n4tot; i += gridDim.x * blockDim.x) {
    bf16x4 o;
    if (i < n4src) {
      float4 f = ((const float4*)src)[i];
      o[0] = (bf16_t)f.x; o[1] = (bf16_t)f.y; o[2] = (bf16_t)f.z; o[3] = (bf16_t)f.w;
    } else {
      o[0] = (bf16_t)0.0f; o[1] = (bf16_t)0.0f; o[2] = (bf16_t)0.0f; o[3] = (bf16_t)0.0f;
    }
    *(bf16x4*)(dst + (size_t)i * 4) = o;
  }
}

__global__ void concat_bias3(const float* __restrict__ a, const float* __restrict__ b,
                             const float* __restrict__ c, float* __restrict__ dst) {
  int i = blockIdx.x * blockDim.x + threadIdx.x;
  if (i < 1024) dst[i] = a[i];
  else if (i < 2048) dst[i] = b[i - 1024];
  else if (i < 3072) dst[i] = c[i - 2048];
}

// ---------------- GEMM: C = act(A @ Bw^T + bias), 256x256 tile, pipelined ----------------
// 512 threads = 8 waves (2 M x 4 N), each wave owns a 128x64 output sub-tile
// (acc[8][4] of 16x16 frags). LDS: 4-slot ring of (A 256x32 + B 256x32) bf16
// = 128 KiB dynamic. Stage tile j+3 while computing j; steady wait vmcnt(8).
// LDS swizzle: byte ^= (((row>>1)&3)<<4); gload_lds dest linear, source col
// pre-swizzled with the same involution.
template<bool BDIAG, bool RELU, bool OUT_BF16>
__global__ __launch_bounds__(512, 2)
void gemm256(const bf16_t* __restrict__ A, int lda,
             const bf16_t* __restrict__ Bw, int ldb,
             const float* __restrict__ bias,
             void* __restrict__ Cout, int ldc,
             int K, int Nmask, int nbx)
{
  extern __shared__ char lds[];
  bf16_t* Ab = (bf16_t*)lds;               // 4 slots x 8192 elems (16 KiB/slot)
  bf16_t* Bb = (bf16_t*)(lds + 65536);

  const int t   = threadIdx.x;
  const int ln  = t & 63;
  const int w   = t >> 6;
  const int l15 = ln & 15, lhi = ln >> 4;
  const int wm  = w >> 2, wn = w & 3;

  // XCD-chunked block swizzle (grid divisible by 8)
  const int nb = (int)gridDim.x;
  const int id = (int)blockIdx.x;
  const int id_sw = (id & 7) * (nb >> 3) + (id >> 3);
  const int bx = id_sw % nbx, by = id_sw / nbx;
  const int rowBase = by * 256;
  const int colBase = bx * 256;
  const int aCol0 = BDIAG ? (colBase >> 10) * 512 : 0;

  // staging decomposition: load i of wave w, lane ln ->
  //   LDS linear byte = i*8192 + w*1024 + ln*16  (row = i*128 + w*16 + ln/4)
  //   source col pre-swizzled: ((ln&3) ^ ((ln>>3)&3)) * 8
  const int srow = (w << 4) + (ln >> 2);
  const int scol = (((ln & 3) ^ (ln >> 3)) & 3) << 3;

  const bf16_t* aS = A  + (size_t)(rowBase + srow) * lda + aCol0 + scol;
  const bf16_t* bS = Bw + (size_t)(colBase + srow) * ldb + scol;
  const size_t aI = (size_t)128 * lda;
  const size_t bI = (size_t)128 * ldb;
  bf16_t* daW = Ab + (w << 9);   // + slot*8192 + i*4096 (+ lane*8 by HW)
  bf16_t* dbW = Bb + (w << 9);

  // fragment read offsets (elements), swizzled
  const int key  = (l15 >> 1) & 3;
  const int fcol = (lhi ^ key) << 3;
  const int aOff = (wm * 128 + l15) * 32 + fcol;   // + mf*512 + slot*8192
  const int bOff = (wn * 64  + l15) * 32 + fcol;   // + nf*512 + slot*8192

  const int nt = K >> 5;

  f32x4 acc[8][4] = {};

  #define STAGE(kt, s)                                                              \
    do {                                                                            \
      const bf16_t* a_ = aS + (size_t)(kt) * 32;                                    \
      const bf16_t* b_ = bS + (size_t)(kt) * 32;                                    \
      bf16_t* da_ = daW + (s) * 8192;                                               \
      bf16_t* db_ = dbW + (s) * 8192;                                               \
      __builtin_amdgcn_global_load_lds(AS1(a_),      AS3(da_),        16, 0, 0);    \
      __builtin_amdgcn_global_load_lds(AS1(a_ + aI), AS3(da_ + 4096), 16, 0, 0);    \
      __builtin_amdgcn_global_load_lds(AS1(b_),      AS3(db_),        16, 0, 0);    \
      __builtin_amdgcn_global_load_lds(AS1(b_ + bI), AS3(db_ + 4096), 16, 0, 0);    \
    } while (0)

  // prologue: stage tiles 0..2, confirm tile 0 (8 = tiles 1,2 still in flight)
  STAGE(0, 0); STAGE(1, 1); STAGE(2, 2);
  asm volatile("s_waitcnt vmcnt(8)" ::: "memory");
  __builtin_amdgcn_s_barrier();
  asm volatile("" ::: "memory");

  for (int j = 0; j < nt; ++j) {
    const int s = j & 3;
    bf16x8 af[8], bf[4];
    #pragma unroll
    for (int mf = 0; mf < 8; ++mf)
      af[mf] = *(const bf16x8*)(Ab + s * 8192 + aOff + mf * 512);
    #pragma unroll
    for (int nf = 0; nf < 4; ++nf)
      bf[nf] = *(const bf16x8*)(Bb + s * 8192 + bOff + nf * 512);

    // prefetch tile j+3 into ring slot (j+3)&3 (slot read in phase j-1, drained)
    if (j + 3 < nt) {
      STAGE(j + 3, ((j + 3) & 3));
      asm volatile("s_waitcnt vmcnt(8)" ::: "memory");   // tile j+1 arrived
    } else if (j + 2 < nt) {
      asm volatile("s_waitcnt vmcnt(4)" ::: "memory");
    } else if (j + 1 < nt) {
      asm volatile("s_waitcnt vmcnt(0)" ::: "memory");
    }
    // drain own ds_reads BEFORE barrier: after the barrier other waves may
    // issue the overwrite of this slot's ring predecessor.
    asm volatile("s_waitcnt lgkmcnt(0)" ::: "memory");
    __builtin_amdgcn_s_barrier();
    asm volatile("" ::: "memory");

    __builtin_amdgcn_s_setprio(1);
    #pragma unroll
    for (int mf = 0; mf < 8; ++mf)
      #pragma unroll
      for (int nf = 0; nf < 4; ++nf)
        acc[mf][nf] = __builtin_amdgcn_mfma_f32_16x16x32_bf16(af[mf], bf[nf], acc[mf][nf], 0, 0, 0);
    __builtin_amdgcn_s_setprio(0);
  }
  #undef STAGE

  // epilogue: C/D layout col=l15, row=lhi*4+i (verified)
  #pragma unroll
  for (int mf = 0; mf < 8; ++mf) {
    const int row = rowBase + wm * 128 + mf * 16 + lhi * 4;
    #pragma unroll
    for (int nf = 0; nf < 4; ++nf) {
      const int col = colBase + wn * 64 + nf * 16 + l15;
      const float bv = (col < Nmask) ? bias[col] : 0.0f;
      #pragma unroll
      for (int i = 0; i < 4; ++i) {
        float v = acc[mf][nf][i] + bv;
        if (RELU) v = fmaxf(v, 0.0f);
        if (OUT_BF16) {
          ((bf16_t*)Cout)[(size_t)(row + i) * ldc + col] = (bf16_t)v;
        } else {
          if (col < Nmask) ((float*)Cout)[(size_t)(row + i) * ldc + col] = v;
        }
      }
    }
  }
}

// ---------------- alphas -> softmax -> context (one block per row) ----------------
__global__ __launch_bounds__(256)
void attn_ctx(const bf16_t* __restrict__ P, bf16_t* __restrict__ ds) {
  __shared__ float red[3][4];
  __shared__ float wsh[3];
  const int r = blockIdx.x;
  const int t = threadIdx.x;
  const bf16_t* Prow = P + (size_t)r * 3072;
  bf16_t* dsrow = ds + (size_t)r * 2048;

  const int j = t * 4;
  bf16x4 lv = *(const bf16x4*)(dsrow + 1024 + j);
  float lhv[4], pv[3][4];
  float s[3] = {0.f, 0.f, 0.f};
  #pragma unroll
  for (int q = 0; q < 4; q++) lhv[q] = (float)lv[q];
  #pragma unroll
  for (int e = 0; e < 3; e++) {
    bf16x4 p = *(const bf16x4*)(Prow + e * 1024 + j);
    #pragma unroll
    for (int q = 0; q < 4; q++) {
      pv[e][q] = (float)p[q];
      s[e] += lhv[q] * pv[e][q];
    }
  }
  #pragma unroll
  for (int off = 32; off > 0; off >>= 1) {
    #pragma unroll
    for (int e = 0; e < 3; e++) s[e] += __shfl_down(s[e], off, 64);
  }
  const int w = t >> 6, l = t & 63;
  if (l == 0) {
    #pragma unroll
    for (int e = 0; e < 3; e++) red[e][w] = s[e];
  }
  __syncthreads();
  if (t == 0) {
    float a0 = red[0][0] + red[0][1] + red[0][2] + red[0][3];
    float a1 = red[1][0] + red[1][1] + red[1][2] + red[1][3];
    float a2 = red[2][0] + red[2][1] + red[2][2] + red[2][3];
    float mx = fmaxf(a0, fmaxf(a1, a2));
    float e0 = expf(a0 - mx), e1 = expf(a1 - mx), e2 = expf(a2 - mx);
    float inv = 1.0f / (e0 + e1 + e2);
    wsh[0] = e0 * inv; wsh[1] = e1 * inv; wsh[2] = e2 * inv;
  }
  __syncthreads();
  const float w0 = wsh[0], w1 = wsh[1], w2 = wsh[2];
  bf16x4 o;
  #pragma unroll
  for (int q = 0; q < 4; q++)
    o[q] = (bf16_t)(w0 * pv[0][q] + w1 * pv[1][q] + w2 * pv[2][q]);
  *(bf16x4*)(dsrow + j) = o;
}

// ---------------- launch ----------------
extern "C" void kernel_launch(void* const* d_in, const int* in_sizes, int n_in,
                              void* d_out, int out_size, void* d_ws, size_t ws_size,
                              hipStream_t stream) {
  (void)in_sizes; (void)n_in; (void)out_size; (void)ws_size;

  const float* tube = (const float*)d_in[0];
  const float* w1W  = (const float*)d_in[1];
  const float* w1b  = (const float*)d_in[2];
  const float* w2W  = (const float*)d_in[3];
  const float* w2b  = (const float*)d_in[4];
  const float* w3W  = (const float*)d_in[5];
  const float* w3b  = (const float*)d_in[6];
  const float* whW  = (const float*)d_in[7];
  const float* whb  = (const float*)d_in[8];
  const float* wd1W = (const float*)d_in[9];
  const float* wd1b = (const float*)d_in[10];
  const float* wd2W = (const float*)d_in[11];
  const float* wd2b = (const float*)d_in[12];

  // workspace layout (bytes); out1 aliases {whB, w123B, tubeB} which are dead by G4.
  char* ws = (char*)d_ws;
  bf16_t* P       = (bf16_t*)(ws + 0);            // 16384x3072
  bf16_t* ds      = (bf16_t*)(ws + 100663296);    // 16384x2048
  bf16_t* wd1B    = (bf16_t*)(ws + 167772160);    // 2048x2048
  bf16_t* wd2B    = (bf16_t*)(ws + 176160768);    // 1024x2048 (rows 1000.. zero)
  bf16_t* whB     = (bf16_t*)(ws + 180355072);    // 1024x3072
  bf16_t* w123B   = (bf16_t*)(ws + 186646528);    // 3072x512
  bf16_t* tubeB   = (bf16_t*)(ws + 189792256);    // 16384x1536
  bf16_t* out1    = (bf16_t*)(ws + 180355072);    // 16384x2048, aliases whB..tubeB
  float*  bias123 = (float*)(ws + 247463936);     // 3072 f32

  // allow 128 KiB dynamic LDS for the gemm instantiations
  hipFuncSetAttribute((const void*)(gemm256<true,  true,  true >),
                      hipFuncAttributeMaxDynamicSharedMemorySize, 131072);
  hipFuncSetAttribute((const void*)(gemm256<false, true,  true >),
                      hipFuncAttributeMaxDynamicSharedMemorySize, 131072);
  hipFuncSetAttribute((const void*)(gemm256<false, false, false>),
                      hipFuncAttributeMaxDynamicSharedMemorySize, 131072);

  auto cvt = [&](const float* s, bf16_t* d, int n4s, int n4t) {
    int nb = (n4t + 255) / 256; if (nb > 2048) nb = 2048;
    hipLaunchKernelGGL(cvt_f32_bf16_v4, dim3(nb), dim3(256), 0, stream, s, d, n4s, n4t);
  };
  cvt(tube, tubeB, 6291456, 6291456);
  cvt(w1W,  w123B,           131072, 131072);
  cvt(w2W,  w123B +  524288, 131072, 131072);
  cvt(w3W,  w123B + 1048576, 131072, 131072);
  cvt(whW,  whB,  786432, 786432);
  cvt(wd1W, wd1B, 1048576, 1048576);
  cvt(wd2W, wd2B, 512000, 524288);
  hipLaunchKernelGGL(concat_bias3, dim3(12), dim3(256), 0, stream, w1b, w2b, w3b, bias123);

  // G1: P = relu(block-diag expert GEMM), N=3072, K=512
  hipLaunchKernelGGL((gemm256<true, true, true>), dim3(12 * 64), dim3(512), 131072, stream,
                     tubeB, 1536, w123B, 512, bias123, (void*)P, 3072, 512, 3072, 12);
  // G2: ds[:,1024:2048] = relu(P @ wh^T + b), N=1024, K=3072
  hipLaunchKernelGGL((gemm256<false, true, true>), dim3(4 * 64), dim3(512), 131072, stream,
                     P, 3072, whB, 3072, whb, (void*)(ds + 1024), 2048, 3072, 1024, 4);
  // attn: alphas -> softmax -> context into ds[:,0:1024]
  hipLaunchKernelGGL(attn_ctx, dim3(16384), dim3(256), 0, stream, P, ds);
  // G4: out1 = relu(ds @ wd1^T + b), N=2048, K=2048
  hipLaunchKernelGGL((gemm256<false, true, true>), dim3(8 * 64), dim3(512), 131072, stream,
                     ds, 2048, wd1B, 2048, wd1b, (void*)out1, 2048, 2048, 2048, 8);
  // G5: out = out1 @ wd2^T + b (fp32, N masked to 1000), K=2048
  hipLaunchKernelGGL((gemm256<false, false, false>), dim3(4 * 64), dim3(512), 131072, stream,
                     out1, 2048, wd2B, 2048, wd2b, d_out, 1000, 2048, 1000, 4);
}